// Round 9
// baseline (488.886 us; speedup 1.0000x reference)
//
#include <hip/hip_runtime.h>
#include <math.h>
#include <limits.h>

#define DIM 2048
#define NEXP 256
#define TOPK 8
#define BM 16
#define BK 16
#define NTH 256
#define NTILE 128

// np-einsum fp32 replica (LOCKED by R3/R4/R6/R8 passes — do not perturb):
//   4 partial chains per output, chain j takes k ≡ j (mod 4);
//   k in 16-groups ascending, within group chunk order 3,2,1,0;
//   separate mul/add rounding (no fma); hadd tree (l0+l1)+(l2+l3);
//   sigmoid in f64 -> f32; pairwise-8 weight sum; ties -> lower index.
// v_pk_*_f32 = element-wise IEEE f32 (bit-identical, halves issue slots).
// R9: counted-vmcnt pipeline (T4): x prefetched distance-2 in a 4-slot LDS
// ring, w distance-1; ONE "s_waitcnt vmcnt(1); s_barrier" per tile (never
// vmcnt(0) in the loop) so the young x load crosses barriers in flight.
// Load issue order per iter MUST be w(t+1) x4 then x(t+2) (vmcnt counts
// oldest-first; the survivor of vmcnt(1) must be x(t+2)).

typedef float f32x2 __attribute__((ext_vector_type(2)));

__device__ __forceinline__ f32x2 pkmul(f32x2 a, f32x2 b) {
    f32x2 d;
    asm("v_pk_mul_f32 %0, %1, %2" : "=v"(d) : "v"(a), "v"(b));
    return d;
}
__device__ __forceinline__ f32x2 pkadd(f32x2 a, f32x2 b) {
    f32x2 d;
    asm("v_pk_add_f32 %0, %1, %2" : "=v"(d) : "v"(a), "v"(b));
    return d;
}

__device__ __forceinline__ void gload16(const void* gptr, void* lptr) {
    __builtin_amdgcn_global_load_lds(
        (const __attribute__((address_space(1))) unsigned int*)(unsigned long long)gptr,
        (__attribute__((address_space(3))) unsigned int*)(unsigned int)(unsigned long long)lptr,
        16, 0, 0);
}

__global__ __launch_bounds__(NTH) void gate_kernel(
    const float* __restrict__ x, const float* __restrict__ w,
    const float* __restrict__ bias, float* __restrict__ outw,
    float* __restrict__ outi)
{
#pragma clang fp contract(off)
    // wbuf[buf]: float idx (c*256 + e)*4 + j  (chunk c=0..3, expert e, j=k%4)
    __shared__ float wbuf[2][4096];   // 32 KB
    __shared__ float xbuf[4][256];    // 4 KB ring, slot = tile&3, [row*16 + k]

    const int tid   = threadIdx.x;
    const int lane  = tid & 63;
    const int elane = tid & 63;              // experts elane + 64*i
    const int r0    = (tid >> 6) * 4;        // 4 rows per thread
    const int gr    = blockIdx.x * BM;

    const char* wsrc = (const char*)w + (size_t)tid * (DIM * 4);  // expert row `tid`
    // every wave stages the whole x tile (redundant, identical bytes; uniform vmcnt)
    const char* xsrc = (const char*)x +
        ((size_t)(gr + (lane >> 2)) * DIM + (lane & 3) * 4) * 4;

    auto stage_w = [&](int buf, int kt) {
        const size_t kb = (size_t)kt * 64;   // 16 floats = 64 B per tile
        char* dst = (char*)&wbuf[buf][0] + tid * 16;
        gload16(wsrc + kb,      dst);
        gload16(wsrc + kb + 16, dst + 4096);
        gload16(wsrc + kb + 32, dst + 8192);
        gload16(wsrc + kb + 48, dst + 12288);
    };
    auto stage_x = [&](int slot, int kt) {
        gload16(xsrc + (size_t)kt * 64, (char*)&xbuf[slot][0] + lane * 16);
    };

    // acc[r][i][p]: p=0 -> chains (j0,j1), p=1 -> chains (j2,j3)
    f32x2 acc[4][4][2];
#pragma unroll
    for (int r = 0; r < 4; ++r)
#pragma unroll
        for (int i = 0; i < 4; ++i)
#pragma unroll
            for (int p = 0; p < 2; ++p) acc[r][i][p] = (f32x2){0.0f, 0.0f};

    auto compute = [&](int buf, int slot) {
#pragma unroll
        for (int c = 3; c >= 0; --c) {          // reversed chunk order in 16-group
            f32x2 xlo[4], xhi[4];
#pragma unroll
            for (int r = 0; r < 4; ++r) {
                const float4 xv = *(const float4*)&xbuf[slot][(r0 + r) * BK + c * 4];
                xlo[r] = (f32x2){xv.x, xv.y};
                xhi[r] = (f32x2){xv.z, xv.w};
            }
#pragma unroll
            for (int i = 0; i < 4; ++i) {
                const float4 wv = *(const float4*)&wbuf[buf][(c * 256 + elane + 64 * i) * 4];
                const f32x2 wlo = (f32x2){wv.x, wv.y};
                const f32x2 whi = (f32x2){wv.z, wv.w};
#pragma unroll
                for (int r = 0; r < 4; ++r) {
                    acc[r][i][0] = pkadd(acc[r][i][0], pkmul(xlo[r], wlo));
                    acc[r][i][1] = pkadd(acc[r][i][1], pkmul(xhi[r], whi));
                }
            }
        }
    };

    // ---- prologue: w(0), x(0), x(1); wait oldest 5, keep x(1) in flight ----
    stage_w(0, 0);
    stage_x(0, 0);
    stage_x(1, 1);
    asm volatile("s_waitcnt vmcnt(1)\ns_barrier" ::: "memory");

    // ---- steady state: entering iter t, outstanding == [x(t+1)] ----
    for (int t = 0; t < 126; ++t) {
        stage_w((t + 1) & 1, t + 1);   // w first (must retire at this iter's wait)
        stage_x((t + 2) & 3, t + 2);   // x last (survives the wait)
        compute(t & 1, t & 3);
        asm volatile("s_waitcnt vmcnt(1)\ns_barrier" ::: "memory");
    }
    // t = 126: nothing left to x-stage
    stage_w(1, 127);
    compute(0, 2);
    asm volatile("s_waitcnt vmcnt(0)\ns_barrier" ::: "memory");
    // t = 127
    compute(1, 3);

    // ---- epilogue: hadd tree + f64 sigmoid -> scores in wbuf[0] ----
    float* sc = &wbuf[0][0];                 // [16][256] = 16 KB (exact fit)
#pragma unroll
    for (int r = 0; r < 4; ++r)
#pragma unroll
        for (int i = 0; i < 4; ++i) {
            const float l01 = acc[r][i][0].x + acc[r][i][0].y;
            const float l23 = acc[r][i][1].x + acc[r][i][1].y;
            const float logit = l01 + l23;
            const double s = 1.0 / (1.0 + exp(-(double)logit));
            sc[(r0 + r) * NEXP + (elane + 64 * i)] = (float)s;
        }
    __syncthreads();

    float* cval = &wbuf[1][0];               // [16][64]
    int*   cidx = (int*)&wbuf[1][1024];      // [16][64]

    // ---- per-row top-8: 8 subs/row on first 128 threads ----
    if (tid < 128) {
        const int row = tid >> 3;
        const int sub = tid & 7;
        float tv[TOPK];
        int   ti[TOPK];
#pragma unroll
        for (int q = 0; q < TOPK; ++q) { tv[q] = -INFINITY; ti[q] = INT_MAX; }
        for (int j = 0; j < 32; ++j) {
            const int e = sub + (j << 3);    // ascending index => stable
            const float v = sc[row * NEXP + e] + bias[e];
            if (v > tv[TOPK - 1]) {
                int p = TOPK - 1;
                while (p > 0 && v > tv[p - 1]) {
                    tv[p] = tv[p - 1]; ti[p] = ti[p - 1]; --p;
                }
                tv[p] = v; ti[p] = e;
            }
        }
#pragma unroll
        for (int q = 0; q < TOPK; ++q) {
            cval[row * 64 + sub * 8 + q] = tv[q];
            cidx[row * 64 + sub * 8 + q] = ti[q];
        }
    }
    __syncthreads();

    // ---- leaders merge 8 sorted lists; ties -> lower index; output ----
    if (tid < 128 && (tid & 7) == 0) {
        const int row = tid >> 3;
        int p[8];
#pragma unroll
        for (int s = 0; s < 8; ++s) p[s] = 0;
        float g[TOPK];
        int   sel[TOPK];
        for (int k = 0; k < TOPK; ++k) {
            float best = -INFINITY;
            int bidx = INT_MAX;
            int bs = 0;
            for (int s = 0; s < 8; ++s) {
                if (p[s] < 8) {
                    const float v = cval[row * 64 + s * 8 + p[s]];
                    const int  id = cidx[row * 64 + s * 8 + p[s]];
                    if (v > best || (v == best && id < bidx)) {
                        best = v; bidx = id; bs = s;
                    }
                }
            }
            p[bs]++;
            sel[k] = bidx;
            g[k] = sc[row * NEXP + bidx];    // original score (no bias)
        }
        const float s01 = g[0] + g[1], s23 = g[2] + g[3];
        const float s45 = g[4] + g[5], s67 = g[6] + g[7];
        const float wsum = (s01 + s23) + (s45 + s67);
        const float den = wsum + 1e-20f;
        const size_t orow = (size_t)(gr + row) * TOPK;
#pragma unroll
        for (int k = 0; k < TOPK; ++k) {
            outw[orow + k] = (g[k] / den) * 2.5f;
            outi[orow + k] = (float)sel[k];
        }
    }
}

extern "C" void kernel_launch(void* const* d_in, const int* in_sizes, int n_in,
                              void* d_out, int out_size, void* d_ws, size_t ws_size,
                              hipStream_t stream) {
    const float* x    = (const float*)d_in[0];
    const float* w    = (const float*)d_in[1];
    const float* bias = (const float*)d_in[2];
    float* outw = (float*)d_out;
    const int M = in_sizes[0] / DIM;              // 16384 rows
    float* outi = outw + (size_t)M * TOPK;
    const int grid = M / BM;                      // 1024 blocks
    hipLaunchKernelGGL(gate_kernel, dim3(grid), dim3(NTH), 0, stream,
                       x, w, bias, outw, outi);
}